// Round 7
// baseline (259.089 us; speedup 1.0000x reference)
//
#include <hip/hip_runtime.h>
#include <cstdint>

using u16 = unsigned short;
using u32 = unsigned int;

typedef __attribute__((ext_vector_type(8))) short short8;   // 8 bf16 (A/B frag)
typedef __attribute__((ext_vector_type(4))) float floatx4;  // C frag

__device__ __forceinline__ u16 f2bf(float f) {
    u32 u = __float_as_uint(f);
    u32 r = u + 0x7fffu + ((u >> 16) & 1u);   // round-to-nearest-even
    return (u16)(r >> 16);
}

// ---------------------------------------------------------------- converts (one dispatch)
// [0,8192): x->bf16 ; [8192,11264): 3 weight mats ; [11264,11272): bias concat ;
// [11272,11280): zero rowsum[8192]
__global__ void cvt_all(const float* __restrict__ x, u16* __restrict__ xb,
                        const float* __restrict__ w0, const float* __restrict__ w1,
                        const float* __restrict__ w2,
                        u16* __restrict__ o0, u16* __restrict__ o1, u16* __restrict__ o2,
                        const float* __restrict__ qb, const float* __restrict__ kb,
                        float* __restrict__ bqk, float* __restrict__ rowsum)
{
    int b = blockIdx.x;
    if (b >= 11272) {              // zero rowsum: 8 blocks x 256 x 4 floats
        long i = ((long)(b - 11272) * 256 + threadIdx.x) * 4;
        *reinterpret_cast<float4*>(rowsum + i) = make_float4(0.f, 0.f, 0.f, 0.f);
        return;
    }
    if (b >= 11264) {              // bias concat: 8 blocks x 256 = 2048
        int i = (b - 11264) * 256 + threadIdx.x;
        bqk[i] = (i < 1024) ? qb[i] : kb[i - 1024];
        return;
    }
    const float* src; u16* dst; long base;
    if (b < 8192) { src = x; dst = xb; base = (long)b; }
    else {
        int r = b - 8192, seg = r >> 10;
        if (seg == 0)      { src = w0; dst = o0; }
        else if (seg == 1) { src = w1; dst = o1; }
        else               { src = w2; dst = o2; }
        base = (long)(r & 1023);
    }
    long i = (base * 256 + threadIdx.x) * 4;
    float4 v = *reinterpret_cast<const float4*>(src + i);
    uint2 o;
    o.x = (u32)f2bf(v.x) | ((u32)f2bf(v.y) << 16);
    o.y = (u32)f2bf(v.z) | ((u32)f2bf(v.w) << 16);
    *reinterpret_cast<uint2*>(dst + i) = o;
}

// ---------------------------------------------------------------- helpers
__device__ __forceinline__ void async_cp16(const u16* g, u16* l) {
    __builtin_amdgcn_global_load_lds(
        (const __attribute__((address_space(1))) void*)g,
        (__attribute__((address_space(3))) void*)l, 16, 0, 0);
}

#define MEMFENCE asm volatile("" ::: "memory")
__device__ __forceinline__ void barrier_raw() {
    MEMFENCE; __builtin_amdgcn_s_barrier(); MEMFENCE;
}
__device__ __forceinline__ void vmwait(int n) {   // folds when n is a literal
    if      (n == 6) asm volatile("s_waitcnt vmcnt(6)" ::: "memory");
    else if (n == 4) asm volatile("s_waitcnt vmcnt(4)" ::: "memory");
    else if (n == 2) asm volatile("s_waitcnt vmcnt(2)" ::: "memory");
    else if (n == 0) asm volatile("s_waitcnt vmcnt(0)" ::: "memory");
}

// ---------------------------------------------------------------- 2-phase GEMM core (NT)
// PROVEN round-0 structure.  128x128 tile, BK=64 (two 32-wide panels), 256 threads,
// 4 waves (each 64x64).  CONVOY NOTE: co-resident blocks traverse K in the SAME order —
// lockstep panel fetches create the L2 reuse.  XCD-contiguous remap outside.
// ROUND-6 (verified): __launch_bounds__(256,4) -> VGPR 64+64acc = 128 = 4 waves/SIMD;
// Occupancy 26->31.5%, fused12 70.2->66.5 us.  Keep.
template <bool BF16_OUT, bool EXPOUT>
__device__ __forceinline__ void gemm_core(
    const u16* __restrict__ A, const u16* __restrict__ B, void* __restrict__ Cv,
    int K, int lda, int ldb, int ldc,
    long tile_m, long tile_n, long cbase,
    const float* bias_col, const float* bias_row,
    float scale, bool rope, float* __restrict__ rowsum,
    const float* __restrict__ rowscale, u16* smem)
{
    u16* As = smem;                 // panels: As + p*4096 (128x32 u16 each)
    u16* Bs = smem + 8192;

    const int tid  = threadIdx.x;
    const int lane = tid & 63;
    const int wave = tid >> 6;
    const int wm = (wave >> 1) << 6;
    const int wn = (wave & 1) << 6;

    floatx4 acc[4][4] = {};

    const int srow = tid >> 2;
    const int skp  = (((tid & 3) ^ (srow & 3))) * 8;
    const u16* Ag = A + (tile_m + srow) * (long)lda + skp;
    const u16* Bg = B + (tile_n + srow) * (long)ldb + skp;
    u16* Asl = &As[tid * 8];
    u16* Bsl = &Bs[tid * 8];

    const int fm  = lane & 15;
    const int fks = (((lane >> 4) ^ (lane & 3))) * 8;   // swizzled k-offset

    for (int k0 = 0; k0 < K; k0 += 64) {
        async_cp16(Ag,                       Asl);
        async_cp16(Ag + 64 * (long)lda,      Asl + 64 * 32);
        async_cp16(Ag + 32,                  Asl + 4096);
        async_cp16(Ag + 32 + 64 * (long)lda, Asl + 4096 + 64 * 32);
        async_cp16(Bg,                       Bsl);
        async_cp16(Bg + 64 * (long)ldb,      Bsl + 64 * 32);
        async_cp16(Bg + 32,                  Bsl + 4096);
        async_cp16(Bg + 32 + 64 * (long)ldb, Bsl + 4096 + 64 * 32);
        Ag += 64; Bg += 64;
        __syncthreads();

        #pragma unroll
        for (int c = 0; c < 2; ++c) {
            const u16* Ap = As + c * 4096;
            const u16* Bp = Bs + c * 4096;
            short8 af[4], bfr[4];
            #pragma unroll
            for (int i = 0; i < 4; ++i)
                af[i] = *reinterpret_cast<const short8*>(&Ap[(wm + i * 16 + fm) * 32 + fks]);
            #pragma unroll
            for (int j = 0; j < 4; ++j)
                bfr[j] = *reinterpret_cast<const short8*>(&Bp[(wn + j * 16 + fm) * 32 + fks]);
            #pragma unroll
            for (int i = 0; i < 4; ++i)
                #pragma unroll
                for (int j = 0; j < 4; ++j)
                    acc[i][j] = __builtin_amdgcn_mfma_f32_16x16x32_bf16(af[i], bfr[j], acc[i][j], 0, 0, 0);
        }
        __syncthreads();
    }

    // epilogue: per-wave LDS transpose -> vectorized stores
    const int q4  = lane >> 4;
    const int c16 = lane & 15;
    float* smemf  = (float*)smem;
    float* myeps = smemf + wave * (16 * 68);
    const long n0 = tile_n + wn + c16 * 4;

    float4 bc4 = make_float4(0.f, 0.f, 0.f, 0.f);
    if (bias_col) bc4 = *reinterpret_cast<const float4*>(bias_col + n0);

    float inv0 = 0.f, inv1 = 0.f;
    if (rope) {
        int p0 = (int)(n0 >> 1);
        inv0 = __expf((float)(p0 & 511)       * -1.79889463e-2f);
        inv1 = __expf((float)((p0 + 1) & 511) * -1.79889463e-2f);
    }

    #pragma unroll
    for (int i = 0; i < 4; ++i) {
        #pragma unroll
        for (int j = 0; j < 4; ++j)
            #pragma unroll
            for (int r = 0; r < 4; ++r)
                myeps[(q4 * 4 + r) * 68 + j * 16 + c16] = acc[i][j][r];
        __syncthreads();
        #pragma unroll
        for (int p = 0; p < 4; ++p) {
            int lrow = p * 4 + q4;
            long m = tile_m + wm + i * 16 + lrow;
            float4 v = *reinterpret_cast<const float4*>(&myeps[lrow * 68 + c16 * 4]);
            float sc = scale;
            if (rowscale) sc *= 1.0f / rowscale[m];
            v.x = v.x * sc + bc4.x;
            v.y = v.y * sc + bc4.y;
            v.z = v.z * sc + bc4.z;
            v.w = v.w * sc + bc4.w;
            if (bias_row) {
                float br = bias_row[m];
                v.x += br; v.y += br; v.z += br; v.w += br;
            }
            if (rope) {
                int s = (int)(m & 2047);
                float a0 = (float)s * inv0, a1 = (float)s * inv1;
                float sn0 = __sinf(a0), cs0 = __cosf(a0);
                float sn1 = __sinf(a1), cs1 = __cosf(a1);
                float x0 = v.x, x1 = v.y, x2 = v.z, x3 = v.w;
                v.x = x0 * cs0 - x1 * sn0;
                v.y = x0 * sn0 + x1 * cs0;
                v.z = x2 * cs1 - x3 * sn1;
                v.w = x2 * sn1 + x3 * cs1;
            }
            if constexpr (EXPOUT) {
                v.x = __expf(v.x); v.y = __expf(v.y);
                v.z = __expf(v.z); v.w = __expf(v.w);
                float s4 = v.x + v.y + v.z + v.w;     // 4 cols of row m
                s4 += __shfl_xor(s4, 1);              // sum across the 16-lane
                s4 += __shfl_xor(s4, 2);              // group holding 64 cols
                s4 += __shfl_xor(s4, 4);
                s4 += __shfl_xor(s4, 8);
                if (c16 == 0) atomicAdd(&rowsum[m], s4);
            }
            long off = cbase + m * (long)ldc + n0;
            if constexpr (BF16_OUT) {
                uint2 o;
                o.x = (u32)f2bf(v.x) | ((u32)f2bf(v.y) << 16);
                o.y = (u32)f2bf(v.z) | ((u32)f2bf(v.w) << 16);
                *reinterpret_cast<uint2*>((u16*)Cv + off) = o;
            } else {
                *reinterpret_cast<float4*>((float*)Cv + off) = v;
            }
        }
        __syncthreads();
    }
}

// ---------------------------------------------------------------- 8-phase 256x256 core
// Kept ONLY for G3 (256-block grid = exactly 1 block/CU, zero tail): measured ~12.5 us
// better than the 2-phase G3.  Do not extend to other GEMMs.
template <bool BF16_OUT, bool EXPOUT>
__device__ __forceinline__ void gemm8_core(
    const u16* __restrict__ A, const u16* __restrict__ B, void* __restrict__ Cv,
    int K, int lda, int ldb, int ldc,
    long tile_m, long tile_n, long cbase,
    const float* __restrict__ bias_col, const float* __restrict__ bias_row,
    float scale, bool rope, float* __restrict__ rowsum, u16* smem)
{
    const int tid  = threadIdx.x;
    const int lane = tid & 63;
    const int wave = tid >> 6;
    const int wm2  = (wave >> 2) * 128;     // wave M offset (0/128)
    const int wn2  = (wave & 3) * 64;       // wave N offset (0/64/128/192)
    const int fm   = lane & 15;
    const int fks  = (((lane >> 4) ^ ((lane >> 1) & 3))) * 8;  // conflict-free k-group read

    const int srow = tid >> 2;                            // 0..127
    const int kgl  = ((tid & 3) ^ ((tid >> 3) & 3)) * 8;  // pre-swizzled source k-group
    const u16* Asrc = A + (tile_m + srow) * (long)lda + kgl;
    const u16* Bsrc = B + (tile_n + srow) * (long)ldb + kgl;
    u16* dst0 = smem + tid * 8;                           // linear LDS dest (gload_lds rule)

    const int U = K >> 5;                                 // #k-substeps (>= 8 here)

    floatx4 acc[8][4] = {};
    short8 bf[4];

    auto stageA = [&](int v) {
        u16* d = dst0 + ((2 * v) & 7) * 8192;
        const u16* s = Asrc + v * 32;
        async_cp16(s, d);
        async_cp16(s + 128 * (long)lda, d + 4096);
    };
    auto stageB = [&](int v) {
        u16* d = dst0 + ((2 * v + 1) & 7) * 8192;
        const u16* s = Bsrc + v * 32;
        async_cp16(s, d);
        async_cp16(s + 128 * (long)ldb, d + 4096);
    };

    auto phase_pair = [&](int u, int vmx, bool stb, bool sta)
        __attribute__((always_inline))
    {
        const u16* Ap = smem + ((2 * u) & 7) * 8192;
        const u16* Bp = smem + ((2 * u + 1) & 7) * 8192;
        short8 af[4];
        #pragma unroll
        for (int i = 0; i < 4; ++i)
            af[i] = *reinterpret_cast<const short8*>(&Ap[(wm2 + i * 16 + fm) * 32 + fks]);
        #pragma unroll
        for (int j = 0; j < 4; ++j)
            bf[j] = *reinterpret_cast<const short8*>(&Bp[(wn2 + j * 16 + fm) * 32 + fks]);
        if (stb) stageB(u + 2);
        vmwait(vmx);
        barrier_raw();
        __builtin_amdgcn_sched_barrier(0);
        __builtin_amdgcn_s_setprio(1);
        #pragma unroll
        for (int i = 0; i < 4; ++i)
            #pragma unroll
            for (int j = 0; j < 4; ++j)
                acc[i][j] = __builtin_amdgcn_mfma_f32_16x16x32_bf16(af[i], bf[j], acc[i][j], 0, 0, 0);
        __builtin_amdgcn_s_setprio(0);
        __builtin_amdgcn_sched_barrier(0);
        barrier_raw();
        #pragma unroll
        for (int i = 0; i < 4; ++i)
            af[i] = *reinterpret_cast<const short8*>(&Ap[(wm2 + 64 + i * 16 + fm) * 32 + fks]);
        if (sta) stageA(u + 3);
        barrier_raw();
        __builtin_amdgcn_sched_barrier(0);
        __builtin_amdgcn_s_setprio(1);
        #pragma unroll
        for (int i = 0; i < 4; ++i)
            #pragma unroll
            for (int j = 0; j < 4; ++j)
                acc[4 + i][j] = __builtin_amdgcn_mfma_f32_16x16x32_bf16(af[i], bf[j], acc[4 + i][j], 0, 0, 0);
        __builtin_amdgcn_s_setprio(0);
        __builtin_amdgcn_sched_barrier(0);
        barrier_raw();
    };

    // prologue: h0..h4 = A0,B0,A1,B1,A2 ; vmcnt(6) confirms A0,B0
    stageA(0); stageB(0); stageA(1); stageB(1); stageA(2);
    vmwait(6);
    barrier_raw();

    for (int u = 0; u + 3 < U; ++u)
        phase_pair(u, 6, true, true);
    phase_pair(U - 3, 6, true,  false);   // X stages B(U-1), last stage
    phase_pair(U - 2, 2, false, false);   // newest1 = B(U-1) -> confirms B(U-2)
    phase_pair(U - 1, 0, false, false);

    // epilogue (identical numerics to 2-phase core, 8 acc rows)
    const int q4  = lane >> 4;
    const int c16 = lane & 15;
    float* smemf  = (float*)smem;
    float* myeps  = smemf + wave * (16 * 68);
    const long n0 = tile_n + wn2 + c16 * 4;

    float4 bc4 = make_float4(0.f, 0.f, 0.f, 0.f);
    if (bias_col) bc4 = *reinterpret_cast<const float4*>(bias_col + n0);

    float inv0 = 0.f, inv1 = 0.f;
    if (rope) {
        int p0 = (int)(n0 >> 1);
        inv0 = __expf((float)(p0 & 511)       * -1.79889463e-2f);
        inv1 = __expf((float)((p0 + 1) & 511) * -1.79889463e-2f);
    }

    #pragma unroll
    for (int i = 0; i < 8; ++i) {
        #pragma unroll
        for (int j = 0; j < 4; ++j)
            #pragma unroll
            for (int r = 0; r < 4; ++r)
                myeps[(q4 * 4 + r) * 68 + j * 16 + c16] = acc[i][j][r];
        __syncthreads();
        #pragma unroll
        for (int p = 0; p < 4; ++p) {
            int lrow = p * 4 + q4;
            long m = tile_m + wm2 + i * 16 + lrow;
            float4 v = *reinterpret_cast<const float4*>(&myeps[lrow * 68 + c16 * 4]);
            v.x = v.x * scale + bc4.x;
            v.y = v.y * scale + bc4.y;
            v.z = v.z * scale + bc4.z;
            v.w = v.w * scale + bc4.w;
            if (bias_row) {
                float br = bias_row[m];
                v.x += br; v.y += br; v.z += br; v.w += br;
            }
            if (rope) {
                int s = (int)(m & 2047);
                float a0 = (float)s * inv0, a1 = (float)s * inv1;
                float sn0 = __sinf(a0), cs0 = __cosf(a0);
                float sn1 = __sinf(a1), cs1 = __cosf(a1);
                float x0 = v.x, x1 = v.y, x2 = v.z, x3 = v.w;
                v.x = x0 * cs0 - x1 * sn0;
                v.y = x0 * sn0 + x1 * cs0;
                v.z = x2 * cs1 - x3 * sn1;
                v.w = x2 * sn1 + x3 * cs1;
            }
            if constexpr (EXPOUT) {
                v.x = __expf(v.x); v.y = __expf(v.y);
                v.z = __expf(v.z); v.w = __expf(v.w);
                float s4 = v.x + v.y + v.z + v.w;
                s4 += __shfl_xor(s4, 1);
                s4 += __shfl_xor(s4, 2);
                s4 += __shfl_xor(s4, 4);
                s4 += __shfl_xor(s4, 8);
                if (c16 == 0) atomicAdd(&rowsum[m], s4);
            }
            long off = cbase + m * (long)ldc + n0;
            if constexpr (BF16_OUT) {
                uint2 o;
                o.x = (u32)f2bf(v.x) | ((u32)f2bf(v.y) << 16);
                o.y = (u32)f2bf(v.z) | ((u32)f2bf(v.w) << 16);
                *reinterpret_cast<uint2*>((u16*)Cv + off) = o;
            } else {
                *reinterpret_cast<float4*>((float*)Cv + off) = v;
            }
        }
        __syncthreads();
    }
}

// fused G1 (QK-proj + RoPE) and G2 (V^T proj): 1536 blocks
__global__ __launch_bounds__(256, 4)
void gemm_fused12(const u16* __restrict__ xb, const u16* __restrict__ wqk,
                  const u16* __restrict__ wv, u16* __restrict__ QK, u16* __restrict__ VT,
                  const float* __restrict__ bqk, const float* __restrict__ wvb)
{
    u32 id = blockIdx.x;                       // 1536
    id = (id & 7u) * 192u + (id >> 3);         // XCD-contiguous remap
    __shared__ alignas(16) u16 smem[16384];
    if (id < 1024u) {
        u32 bx = id & 15u, by = id >> 4;
        gemm_core<true, false>(xb, wqk, QK, 1024, 1024, 1024, 2048,
                        (long)by * 128, (long)bx * 128, 0L,
                        bqk, nullptr, 1.0f, true, nullptr, nullptr, smem);
    } else {
        u32 r = id - 1024u;
        u32 bx = r & 15u, by = (r >> 4) & 7u, bz = r >> 7;
        gemm_core<true, false>(wv, xb + (long)bz * 2048 * 1024, VT,
                        1024, 1024, 1024, 2048,
                        (long)by * 128, (long)bx * 128, (long)bz * 1024 * 2048,
                        nullptr, wvb, 1.0f, false, nullptr, nullptr, smem);
    }
}

// G3: P_unnorm[b] = exp(Q[b] @ K[b]^T / 32) -> bf16, rowsum accumulated.  256 blocks (1/CU)
__global__ __launch_bounds__(512, 2)
void gemm8_qkt(const u16* __restrict__ QK, u16* __restrict__ Pbuf,
               float* __restrict__ rsum)
{
    u32 id = blockIdx.x;
    id = (id & 7u) * 32u + (id >> 3);          // XCD-contiguous remap (256 % 8 == 0)
    u32 bz = id >> 6, q = id & 63u, bx = q & 7u, by = q >> 3;
    __shared__ alignas(16) u16 smem[65536];
    const u16* base = QK + (long)bz * 2048 * 2048;
    gemm8_core<true, true>(base, base + 1024, Pbuf, 1024, 2048, 2048, 2048,
                           nullptr == nullptr ? (long)by * 256 : 0, (long)bx * 256,
                           (long)bz * 2048 * 2048,
                           nullptr, nullptr, 0.03125f, false,
                           rsum + (long)bz * 2048, smem);
}

// G5: out[b] = (P[b] @ VT[b]^T) / rowsum.  ROUND-7: XCD-resident VT mapping.
// VT per batch = 4MB = one XCD's L2.  HW round-robins blockIdx across XCDs (xcd=ord&7,
// same assumption as all existing remaps); pin batch bz to XCD pair {2bz,2bz+1}: each
// XCD's 64 blocks re-read ONE resident VT[bz] (4MB, L2-hit) + stream 8 P-panels.
// HBM traffic ~512MB -> ~64MB; G5 was ~60-65us at ~530 TF (operand-BW-bound by
// elimination: same core+occupancy as fused12's 775 TF, only operand residency differs).
// All 512 blocks co-resident (2/CU <= 4 cap) so reuse needs no convoy timing.
__global__ __launch_bounds__(256, 4)
void gemm_pv(const u16* __restrict__ Pbuf, const u16* __restrict__ VT,
             float* __restrict__ out, const float* __restrict__ rsum)
{
    u32 ord = blockIdx.x;            // 512
    u32 x  = ord & 7u;               // XCD (assumed round-robin)
    u32 n  = ord >> 3;               // 0..63 within XCD
    u32 bz = x >> 1;                 // batch -> XCD pair
    u32 by = (x & 1u) * 8u + (n >> 3);   // 16 M-tiles (8 per XCD of the pair)
    u32 bx = n & 7u;                     // 8 N-tiles
    __shared__ alignas(16) u16 smem[16384];
    gemm_core<false, false>(Pbuf + (long)bz * 2048 * 2048,
                            VT   + (long)bz * 1024 * 2048,
                            out, 2048, 2048, 2048, 1024,
                            (long)by * 128, (long)bx * 128, (long)bz * 2048 * 1024,
                            nullptr, nullptr, 1.0f, false, nullptr,
                            rsum + (long)bz * 2048, smem);
}

// ---------------------------------------------------------------- launch
extern "C" void kernel_launch(void* const* d_in, const int* in_sizes, int n_in,
                              void* d_out, int out_size, void* d_ws, size_t ws_size,
                              hipStream_t stream)
{
    const float* x   = (const float*)d_in[0];
    const float* wqw = (const float*)d_in[1];
    const float* wqb = (const float*)d_in[2];
    const float* wkw = (const float*)d_in[3];
    const float* wkb = (const float*)d_in[4];
    const float* wvw = (const float*)d_in[5];
    const float* wvb = (const float*)d_in[6];
    float* out = (float*)d_out;

    char* ws = (char*)d_ws;
    const size_t MB = 1ull << 20;
    u16*   Pbuf = (u16*)(ws + 64 * MB);      // 32MB [4][2048][2048] bf16 P_unnorm = exp(S)
    u16*   QK   = (u16*)(ws + 96 * MB);      // 32MB [8192][2048] bf16 (Q | K), RoPE applied
    u16*   VT   = (u16*)(ws + 128 * MB);     // 16MB [4][1024][2048] bf16 (V transposed)
    float* rsum = (float*)(ws + 144 * MB);   // 32KB [8192] f32 softmax row sums
    u16*   xb    = (u16*)(ws + 0);           // 16MB [8192][1024]
    u16*   wqk   = (u16*)(ws + 16 * MB);     //  4MB [2048][1024]
    u16*   wvbuf = (u16*)(ws + 20 * MB);     //  2MB [1024][1024]
    float* bqk   = (float*)(ws + 22 * MB);   //  8KB [2048]

    // 1. all dtype conversions + bias concat + rowsum zeroing
    cvt_all<<<dim3(11280), 256, 0, stream>>>(x, xb, wqw, wkw, wvw,
                                             wqk, wqk + 1024 * 1024, wvbuf,
                                             wqb, wkb, bqk, rsum);

    // 2. fused G1 + G2 (2-phase 128^2 core, 4 blocks/CU)
    gemm_fused12<<<dim3(1536), 256, 0, stream>>>(xb, wqk, wvbuf, QK, VT, bqk, wvb);

    // 3. G3 on the 8-phase core (256 blocks, zero tail — measured win, kept)
    gemm8_qkt<<<dim3(256), 512, 0, stream>>>(QK, Pbuf, rsum);

    // 4. G5 with XCD-resident VT (512 blocks, all co-resident)
    gemm_pv<<<dim3(512), 256, 0, stream>>>(Pbuf, VT, out, rsum);

    (void)in_sizes; (void)n_in; (void)out_size; (void)ws_size;
}

// Round 8
// 236.680 us; speedup vs baseline: 1.0947x; 1.0947x over previous
//
#include <hip/hip_runtime.h>
#include <cstdint>

using u16 = unsigned short;
using u32 = unsigned int;

typedef __attribute__((ext_vector_type(8))) short short8;   // 8 bf16 (A/B frag)
typedef __attribute__((ext_vector_type(4))) float floatx4;  // C frag

__device__ __forceinline__ u16 f2bf(float f) {
    u32 u = __float_as_uint(f);
    u32 r = u + 0x7fffu + ((u >> 16) & 1u);   // round-to-nearest-even
    return (u16)(r >> 16);
}

// ---------------------------------------------------------------- converts (one dispatch)
__global__ void cvt_all(const float* __restrict__ x, u16* __restrict__ xb,
                        const float* __restrict__ w0, const float* __restrict__ w1,
                        const float* __restrict__ w2,
                        u16* __restrict__ o0, u16* __restrict__ o1, u16* __restrict__ o2,
                        const float* __restrict__ qb, const float* __restrict__ kb,
                        float* __restrict__ bqk, float* __restrict__ rowsum)
{
    int b = blockIdx.x;
    if (b >= 11272) {              // zero rowsum: 8 blocks x 256 x 4 floats
        long i = ((long)(b - 11272) * 256 + threadIdx.x) * 4;
        *reinterpret_cast<float4*>(rowsum + i) = make_float4(0.f, 0.f, 0.f, 0.f);
        return;
    }
    if (b >= 11264) {              // bias concat: 8 blocks x 256 = 2048
        int i = (b - 11264) * 256 + threadIdx.x;
        bqk[i] = (i < 1024) ? qb[i] : kb[i - 1024];
        return;
    }
    const float* src; u16* dst; long base;
    if (b < 8192) { src = x; dst = xb; base = (long)b; }
    else {
        int r = b - 8192, seg = r >> 10;
        if (seg == 0)      { src = w0; dst = o0; }
        else if (seg == 1) { src = w1; dst = o1; }
        else               { src = w2; dst = o2; }
        base = (long)(r & 1023);
    }
    long i = (base * 256 + threadIdx.x) * 4;
    float4 v = *reinterpret_cast<const float4*>(src + i);
    uint2 o;
    o.x = (u32)f2bf(v.x) | ((u32)f2bf(v.y) << 16);
    o.y = (u32)f2bf(v.z) | ((u32)f2bf(v.w) << 16);
    *reinterpret_cast<uint2*>(dst + i) = o;
}

// ---------------------------------------------------------------- helpers
__device__ __forceinline__ void async_cp16(const u16* g, u16* l) {
    __builtin_amdgcn_global_load_lds(
        (const __attribute__((address_space(1))) void*)g,
        (__attribute__((address_space(3))) void*)l, 16, 0, 0);
}

#define MEMFENCE asm volatile("" ::: "memory")
__device__ __forceinline__ void barrier_raw() {
    MEMFENCE; __builtin_amdgcn_s_barrier(); MEMFENCE;
}
__device__ __forceinline__ void vmwait(int n) {   // folds when n is a literal
    if      (n == 6) asm volatile("s_waitcnt vmcnt(6)" ::: "memory");
    else if (n == 5) asm volatile("s_waitcnt vmcnt(5)" ::: "memory");
    else if (n == 4) asm volatile("s_waitcnt vmcnt(4)" ::: "memory");
    else if (n == 3) asm volatile("s_waitcnt vmcnt(3)" ::: "memory");
    else if (n == 2) asm volatile("s_waitcnt vmcnt(2)" ::: "memory");
    else if (n == 0) asm volatile("s_waitcnt vmcnt(0)" ::: "memory");
}

// ---------------------------------------------------------------- 2-phase GEMM core (NT)
// PROVEN round-0 structure.  128x128 tile, BK=64, 256 threads, 4 waves (each 64x64).
// CONVOY NOTE: co-resident blocks traverse K in the SAME order.
// ROUND-6 (verified): __launch_bounds__(256,4) -> VGPR 64+64acc = 128 = 4 waves/SIMD;
// Occupancy 26->31.5%, fused12 70.2->66.5 us.  At the 2-phase structure ceiling (~786 TF).
template <bool BF16_OUT, bool EXPOUT>
__device__ __forceinline__ void gemm_core(
    const u16* __restrict__ A, const u16* __restrict__ B, void* __restrict__ Cv,
    int K, int lda, int ldb, int ldc,
    long tile_m, long tile_n, long cbase,
    const float* bias_col, const float* bias_row,
    float scale, bool rope, float* __restrict__ rowsum,
    const float* __restrict__ rowscale, u16* smem)
{
    u16* As = smem;                 // panels: As + p*4096 (128x32 u16 each)
    u16* Bs = smem + 8192;

    const int tid  = threadIdx.x;
    const int lane = tid & 63;
    const int wave = tid >> 6;
    const int wm = (wave >> 1) << 6;
    const int wn = (wave & 1) << 6;

    floatx4 acc[4][4] = {};

    const int srow = tid >> 2;
    const int skp  = (((tid & 3) ^ (srow & 3))) * 8;
    const u16* Ag = A + (tile_m + srow) * (long)lda + skp;
    const u16* Bg = B + (tile_n + srow) * (long)ldb + skp;
    u16* Asl = &As[tid * 8];
    u16* Bsl = &Bs[tid * 8];

    const int fm  = lane & 15;
    const int fks = (((lane >> 4) ^ (lane & 3))) * 8;   // swizzled k-offset

    for (int k0 = 0; k0 < K; k0 += 64) {
        async_cp16(Ag,                       Asl);
        async_cp16(Ag + 64 * (long)lda,      Asl + 64 * 32);
        async_cp16(Ag + 32,                  Asl + 4096);
        async_cp16(Ag + 32 + 64 * (long)lda, Asl + 4096 + 64 * 32);
        async_cp16(Bg,                       Bsl);
        async_cp16(Bg + 64 * (long)ldb,      Bsl + 64 * 32);
        async_cp16(Bg + 32,                  Bsl + 4096);
        async_cp16(Bg + 32 + 64 * (long)ldb, Bsl + 4096 + 64 * 32);
        Ag += 64; Bg += 64;
        __syncthreads();

        #pragma unroll
        for (int c = 0; c < 2; ++c) {
            const u16* Ap = As + c * 4096;
            const u16* Bp = Bs + c * 4096;
            short8 af[4], bfr[4];
            #pragma unroll
            for (int i = 0; i < 4; ++i)
                af[i] = *reinterpret_cast<const short8*>(&Ap[(wm + i * 16 + fm) * 32 + fks]);
            #pragma unroll
            for (int j = 0; j < 4; ++j)
                bfr[j] = *reinterpret_cast<const short8*>(&Bp[(wn + j * 16 + fm) * 32 + fks]);
            #pragma unroll
            for (int i = 0; i < 4; ++i)
                #pragma unroll
                for (int j = 0; j < 4; ++j)
                    acc[i][j] = __builtin_amdgcn_mfma_f32_16x16x32_bf16(af[i], bfr[j], acc[i][j], 0, 0, 0);
        }
        __syncthreads();
    }

    // epilogue: per-wave LDS transpose -> vectorized stores
    const int q4  = lane >> 4;
    const int c16 = lane & 15;
    float* smemf  = (float*)smem;
    float* myeps = smemf + wave * (16 * 68);
    const long n0 = tile_n + wn + c16 * 4;

    float4 bc4 = make_float4(0.f, 0.f, 0.f, 0.f);
    if (bias_col) bc4 = *reinterpret_cast<const float4*>(bias_col + n0);

    float inv0 = 0.f, inv1 = 0.f;
    if (rope) {
        int p0 = (int)(n0 >> 1);
        inv0 = __expf((float)(p0 & 511)       * -1.79889463e-2f);
        inv1 = __expf((float)((p0 + 1) & 511) * -1.79889463e-2f);
    }

    #pragma unroll
    for (int i = 0; i < 4; ++i) {
        #pragma unroll
        for (int j = 0; j < 4; ++j)
            #pragma unroll
            for (int r = 0; r < 4; ++r)
                myeps[(q4 * 4 + r) * 68 + j * 16 + c16] = acc[i][j][r];
        __syncthreads();
        #pragma unroll
        for (int p = 0; p < 4; ++p) {
            int lrow = p * 4 + q4;
            long m = tile_m + wm + i * 16 + lrow;
            float4 v = *reinterpret_cast<const float4*>(&myeps[lrow * 68 + c16 * 4]);
            float sc = scale;
            if (rowscale) sc *= 1.0f / rowscale[m];
            v.x = v.x * sc + bc4.x;
            v.y = v.y * sc + bc4.y;
            v.z = v.z * sc + bc4.z;
            v.w = v.w * sc + bc4.w;
            if (bias_row) {
                float br = bias_row[m];
                v.x += br; v.y += br; v.z += br; v.w += br;
            }
            if (rope) {
                int s = (int)(m & 2047);
                float a0 = (float)s * inv0, a1 = (float)s * inv1;
                float sn0 = __sinf(a0), cs0 = __cosf(a0);
                float sn1 = __sinf(a1), cs1 = __cosf(a1);
                float x0 = v.x, x1 = v.y, x2 = v.z, x3 = v.w;
                v.x = x0 * cs0 - x1 * sn0;
                v.y = x0 * sn0 + x1 * cs0;
                v.z = x2 * cs1 - x3 * sn1;
                v.w = x2 * sn1 + x3 * cs1;
            }
            if constexpr (EXPOUT) {
                v.x = __expf(v.x); v.y = __expf(v.y);
                v.z = __expf(v.z); v.w = __expf(v.w);
                float s4 = v.x + v.y + v.z + v.w;     // 4 cols of row m
                s4 += __shfl_xor(s4, 1);              // sum across the 16-lane
                s4 += __shfl_xor(s4, 2);              // group holding 64 cols
                s4 += __shfl_xor(s4, 4);
                s4 += __shfl_xor(s4, 8);
                if (c16 == 0) atomicAdd(&rowsum[m], s4);
            }
            long off = cbase + m * (long)ldc + n0;
            if constexpr (BF16_OUT) {
                uint2 o;
                o.x = (u32)f2bf(v.x) | ((u32)f2bf(v.y) << 16);
                o.y = (u32)f2bf(v.z) | ((u32)f2bf(v.w) << 16);
                *reinterpret_cast<uint2*>((u16*)Cv + off) = o;
            } else {
                *reinterpret_cast<float4*>((float*)Cv + off) = v;
            }
        }
        __syncthreads();
    }
}

// ---------------------------------------------------------------- 8-phase 256x256 core
// Kept for G3 (256-block grid = 1 block/CU, zero tail).  Unchanged, passing since r1.
template <bool BF16_OUT, bool EXPOUT>
__device__ __forceinline__ void gemm8_core(
    const u16* __restrict__ A, const u16* __restrict__ B, void* __restrict__ Cv,
    int K, int lda, int ldb, int ldc,
    long tile_m, long tile_n, long cbase,
    const float* __restrict__ bias_col, const float* __restrict__ bias_row,
    float scale, bool rope, float* __restrict__ rowsum, u16* smem)
{
    const int tid  = threadIdx.x;
    const int lane = tid & 63;
    const int wave = tid >> 6;
    const int wm2  = (wave >> 2) * 128;     // wave M offset (0/128)
    const int wn2  = (wave & 3) * 64;       // wave N offset (0/64/128/192)
    const int fm   = lane & 15;
    const int fks  = (((lane >> 4) ^ ((lane >> 1) & 3))) * 8;  // conflict-free k-group read

    const int srow = tid >> 2;                            // 0..127
    const int kgl  = ((tid & 3) ^ ((tid >> 3) & 3)) * 8;  // pre-swizzled source k-group
    const u16* Asrc = A + (tile_m + srow) * (long)lda + kgl;
    const u16* Bsrc = B + (tile_n + srow) * (long)ldb + kgl;
    u16* dst0 = smem + tid * 8;                           // linear LDS dest (gload_lds rule)

    const int U = K >> 5;                                 // #k-substeps (>= 8 here)

    floatx4 acc[8][4] = {};
    short8 bf[4];

    auto stageA = [&](int v) {
        u16* d = dst0 + ((2 * v) & 7) * 8192;
        const u16* s = Asrc + v * 32;
        async_cp16(s, d);
        async_cp16(s + 128 * (long)lda, d + 4096);
    };
    auto stageB = [&](int v) {
        u16* d = dst0 + ((2 * v + 1) & 7) * 8192;
        const u16* s = Bsrc + v * 32;
        async_cp16(s, d);
        async_cp16(s + 128 * (long)ldb, d + 4096);
    };

    auto phase_pair = [&](int u, int vmx, bool stb, bool sta)
        __attribute__((always_inline))
    {
        const u16* Ap = smem + ((2 * u) & 7) * 8192;
        const u16* Bp = smem + ((2 * u + 1) & 7) * 8192;
        short8 af[4];
        #pragma unroll
        for (int i = 0; i < 4; ++i)
            af[i] = *reinterpret_cast<const short8*>(&Ap[(wm2 + i * 16 + fm) * 32 + fks]);
        #pragma unroll
        for (int j = 0; j < 4; ++j)
            bf[j] = *reinterpret_cast<const short8*>(&Bp[(wn2 + j * 16 + fm) * 32 + fks]);
        if (stb) stageB(u + 2);
        vmwait(vmx);
        barrier_raw();
        __builtin_amdgcn_sched_barrier(0);
        __builtin_amdgcn_s_setprio(1);
        #pragma unroll
        for (int i = 0; i < 4; ++i)
            #pragma unroll
            for (int j = 0; j < 4; ++j)
                acc[i][j] = __builtin_amdgcn_mfma_f32_16x16x32_bf16(af[i], bf[j], acc[i][j], 0, 0, 0);
        __builtin_amdgcn_s_setprio(0);
        __builtin_amdgcn_sched_barrier(0);
        barrier_raw();
        #pragma unroll
        for (int i = 0; i < 4; ++i)
            af[i] = *reinterpret_cast<const short8*>(&Ap[(wm2 + 64 + i * 16 + fm) * 32 + fks]);
        if (sta) stageA(u + 3);
        barrier_raw();
        __builtin_amdgcn_sched_barrier(0);
        __builtin_amdgcn_s_setprio(1);
        #pragma unroll
        for (int i = 0; i < 4; ++i)
            #pragma unroll
            for (int j = 0; j < 4; ++j)
                acc[4 + i][j] = __builtin_amdgcn_mfma_f32_16x16x32_bf16(af[i], bf[j], acc[4 + i][j], 0, 0, 0);
        __builtin_amdgcn_s_setprio(0);
        __builtin_amdgcn_sched_barrier(0);
        barrier_raw();
    };

    // prologue: h0..h4 = A0,B0,A1,B1,A2 ; vmcnt(6) confirms A0,B0
    stageA(0); stageB(0); stageA(1); stageB(1); stageA(2);
    vmwait(6);
    barrier_raw();

    for (int u = 0; u + 3 < U; ++u)
        phase_pair(u, 6, true, true);
    phase_pair(U - 3, 6, true,  false);   // X stages B(U-1), last stage
    phase_pair(U - 2, 2, false, false);   // newest1 = B(U-1) -> confirms B(U-2)
    phase_pair(U - 1, 0, false, false);

    // epilogue (identical numerics to 2-phase core, 8 acc rows)
    const int q4  = lane >> 4;
    const int c16 = lane & 15;
    float* smemf  = (float*)smem;
    float* myeps  = smemf + wave * (16 * 68);
    const long n0 = tile_n + wn2 + c16 * 4;

    float4 bc4 = make_float4(0.f, 0.f, 0.f, 0.f);
    if (bias_col) bc4 = *reinterpret_cast<const float4*>(bias_col + n0);

    float inv0 = 0.f, inv1 = 0.f;
    if (rope) {
        int p0 = (int)(n0 >> 1);
        inv0 = __expf((float)(p0 & 511)       * -1.79889463e-2f);
        inv1 = __expf((float)((p0 + 1) & 511) * -1.79889463e-2f);
    }

    #pragma unroll
    for (int i = 0; i < 8; ++i) {
        #pragma unroll
        for (int j = 0; j < 4; ++j)
            #pragma unroll
            for (int r = 0; r < 4; ++r)
                myeps[(q4 * 4 + r) * 68 + j * 16 + c16] = acc[i][j][r];
        __syncthreads();
        #pragma unroll
        for (int p = 0; p < 4; ++p) {
            int lrow = p * 4 + q4;
            long m = tile_m + wm2 + i * 16 + lrow;
            float4 v = *reinterpret_cast<const float4*>(&myeps[lrow * 68 + c16 * 4]);
            v.x = v.x * scale + bc4.x;
            v.y = v.y * scale + bc4.y;
            v.z = v.z * scale + bc4.z;
            v.w = v.w * scale + bc4.w;
            if (bias_row) {
                float br = bias_row[m];
                v.x += br; v.y += br; v.z += br; v.w += br;
            }
            if (rope) {
                int s = (int)(m & 2047);
                float a0 = (float)s * inv0, a1 = (float)s * inv1;
                float sn0 = __sinf(a0), cs0 = __cosf(a0);
                float sn1 = __sinf(a1), cs1 = __cosf(a1);
                float x0 = v.x, x1 = v.y, x2 = v.z, x3 = v.w;
                v.x = x0 * cs0 - x1 * sn0;
                v.y = x0 * sn0 + x1 * cs0;
                v.z = x2 * cs1 - x3 * sn1;
                v.w = x2 * sn1 + x3 * cs1;
            }
            if constexpr (EXPOUT) {
                v.x = __expf(v.x); v.y = __expf(v.y);
                v.z = __expf(v.z); v.w = __expf(v.w);
                float s4 = v.x + v.y + v.z + v.w;
                s4 += __shfl_xor(s4, 1);
                s4 += __shfl_xor(s4, 2);
                s4 += __shfl_xor(s4, 4);
                s4 += __shfl_xor(s4, 8);
                if (c16 == 0) atomicAdd(&rowsum[m], s4);
            }
            long off = cbase + m * (long)ldc + n0;
            if constexpr (BF16_OUT) {
                uint2 o;
                o.x = (u32)f2bf(v.x) | ((u32)f2bf(v.y) << 16);
                o.y = (u32)f2bf(v.z) | ((u32)f2bf(v.w) << 16);
                *reinterpret_cast<uint2*>((u16*)Cv + off) = o;
            } else {
                *reinterpret_cast<float4*>((float*)Cv + off) = v;
            }
        }
        __syncthreads();
    }
}

// ---------------------------------------------------------------- 8-phase 256x128 core (G5)
// ROUND-8: G5 on the 8-phase structure with BM=256, BN=128 -> grid 256 blocks = 1/CU,
// zero tail (the 2-phase G5's 512 blocks sat at 2 blocks/CU with no second round —
// half of fused12's effective occupancy, and r4 showed retiling at same occupancy is null).
// Staging: A half-tile 256x32 = 2 issues; B half-tile 128x32 = 1 issue.  LDS ring =
// 4 slots x (16KB A + 8KB B) = 96KB.  Ledger (issues): prologue A0,B0,A1,B1,A2 = 8;
// vmcnt(5) confirms A0(2)+B0(1).  Steady X(u): after staging B(u+2), newest 3 =
// A(u+2)(2)+B(u+2)(1) -> vmcnt(3) confirms A(u+1),B(u+1) BEFORE X(u+1)'s ds_reads
// (race-free; stricter than the 256^2 core's discipline).  Tail: 3 (u=U-3, stages
// B(U-1) last), 0, 0.  Slot reuse: A(u+4) staged at Y(u+1), last read of A(u) at Y(u),
// >=3 barriers apart; B(u+4) staged at X(u+2), last read of B(u) at X(u)  [ok].
__device__ __forceinline__ void gemm8n128_core(
    const u16* __restrict__ A, const u16* __restrict__ B, float* __restrict__ C,
    int K, int lda, int ldb, int ldc,
    long tile_m, long tile_n, long cbase,
    const float* __restrict__ rowscale, u16* smem)
{
    const int tid  = threadIdx.x;
    const int lane = tid & 63;
    const int wave = tid >> 6;
    const int wm2  = (wave >> 2) * 128;     // wave M offset (0/128)
    const int wn2  = (wave & 3) * 32;       // wave N offset (0/32/64/96)
    const int fm   = lane & 15;
    const int fks  = (((lane >> 4) ^ ((lane >> 1) & 3))) * 8;

    const int srow = tid >> 2;                            // 0..127
    const int kgl  = ((tid & 3) ^ ((tid >> 3) & 3)) * 8;  // pre-swizzled source k-group
    const u16* Asrc = A + (tile_m + srow) * (long)lda + kgl;
    const u16* Bsrc = B + (tile_n + srow) * (long)ldb + kgl;   // rows 0..127
    u16* dst0 = smem + tid * 8;

    const int U = K >> 5;                                 // 64 for K=2048

    floatx4 acc[8][2] = {};
    short8 bf[2];

    auto stageA = [&](int v) {
        u16* d = dst0 + (v & 3) * 12288;                  // A slot: 16KB (8192 u16)
        const u16* s = Asrc + v * 32;
        async_cp16(s, d);
        async_cp16(s + 128 * (long)lda, d + 4096);
    };
    auto stageB = [&](int v) {                            // B slot: 8KB, single issue
        async_cp16(Bsrc + v * 32, dst0 + (v & 3) * 12288 + 8192);
    };

    auto phase_pair = [&](int u, int vmx, bool stb, bool sta)
        __attribute__((always_inline))
    {
        const u16* Ap = smem + (u & 3) * 12288;
        const u16* Bp = Ap + 8192;
        short8 af[4];
        #pragma unroll
        for (int i = 0; i < 4; ++i)
            af[i] = *reinterpret_cast<const short8*>(&Ap[(wm2 + i * 16 + fm) * 32 + fks]);
        #pragma unroll
        for (int j = 0; j < 2; ++j)
            bf[j] = *reinterpret_cast<const short8*>(&Bp[(wn2 + j * 16 + fm) * 32 + fks]);
        if (stb) stageB(u + 2);
        vmwait(vmx);
        barrier_raw();
        __builtin_amdgcn_sched_barrier(0);
        __builtin_amdgcn_s_setprio(1);
        #pragma unroll
        for (int i = 0; i < 4; ++i)
            #pragma unroll
            for (int j = 0; j < 2; ++j)
                acc[i][j] = __builtin_amdgcn_mfma_f32_16x16x32_bf16(af[i], bf[j], acc[i][j], 0, 0, 0);
        __builtin_amdgcn_s_setprio(0);
        __builtin_amdgcn_sched_barrier(0);
        barrier_raw();
        #pragma unroll
        for (int i = 0; i < 4; ++i)
            af[i] = *reinterpret_cast<const short8*>(&Ap[(wm2 + 64 + i * 16 + fm) * 32 + fks]);
        if (sta) stageA(u + 3);
        barrier_raw();
        __builtin_amdgcn_sched_barrier(0);
        __builtin_amdgcn_s_setprio(1);
        #pragma unroll
        for (int i = 0; i < 4; ++i)
            #pragma unroll
            for (int j = 0; j < 2; ++j)
                acc[4 + i][j] = __builtin_amdgcn_mfma_f32_16x16x32_bf16(af[i], bf[j], acc[4 + i][j], 0, 0, 0);
        __builtin_amdgcn_s_setprio(0);
        __builtin_amdgcn_sched_barrier(0);
        barrier_raw();
    };

    // prologue: A0,B0,A1,B1,A2 = 8 issues; vmcnt(5) confirms A0+B0
    stageA(0); stageB(0); stageA(1); stageB(1); stageA(2);
    vmwait(5);
    barrier_raw();

    for (int u = 0; u + 3 < U; ++u)
        phase_pair(u, 3, true, true);
    phase_pair(U - 3, 3, true,  false);   // stages B(U-1), last issue
    phase_pair(U - 2, 0, false, false);
    phase_pair(U - 1, 0, false, false);

    // epilogue: n64-proven pattern (stride-36 transpose, float2), 8 acc rows,
    // rowscale division, f32 out
    const int q4  = lane >> 4;
    const int c16 = lane & 15;
    float* smemf = (float*)smem;
    float* myeps = smemf + wave * (16 * 36);
    const long n0 = tile_n + wn2 + c16 * 2;

    #pragma unroll
    for (int i = 0; i < 8; ++i) {
        #pragma unroll
        for (int j = 0; j < 2; ++j)
            #pragma unroll
            for (int r = 0; r < 4; ++r)
                myeps[(q4 * 4 + r) * 36 + j * 16 + c16] = acc[i][j][r];
        __syncthreads();
        #pragma unroll
        for (int p = 0; p < 4; ++p) {
            int lrow = p * 4 + q4;
            long m = tile_m + wm2 + i * 16 + lrow;
            float2 v = *reinterpret_cast<const float2*>(&myeps[lrow * 36 + c16 * 2]);
            float sc = 1.0f / rowscale[m];
            v.x *= sc; v.y *= sc;
            *reinterpret_cast<float2*>(C + cbase + m * (long)ldc + n0) = v;
        }
        __syncthreads();
    }
}

// fused G1 (QK-proj + RoPE) and G2 (V^T proj): 1536 blocks, 4 blocks/CU
__global__ __launch_bounds__(256, 4)
void gemm_fused12(const u16* __restrict__ xb, const u16* __restrict__ wqk,
                  const u16* __restrict__ wv, u16* __restrict__ QK, u16* __restrict__ VT,
                  const float* __restrict__ bqk, const float* __restrict__ wvb)
{
    u32 id = blockIdx.x;                       // 1536
    id = (id & 7u) * 192u + (id >> 3);         // XCD-contiguous remap
    __shared__ alignas(16) u16 smem[16384];
    if (id < 1024u) {
        u32 bx = id & 15u, by = id >> 4;
        gemm_core<true, false>(xb, wqk, QK, 1024, 1024, 1024, 2048,
                        (long)by * 128, (long)bx * 128, 0L,
                        bqk, nullptr, 1.0f, true, nullptr, nullptr, smem);
    } else {
        u32 r = id - 1024u;
        u32 bx = r & 15u, by = (r >> 4) & 7u, bz = r >> 7;
        gemm_core<true, false>(wv, xb + (long)bz * 2048 * 1024, VT,
                        1024, 1024, 1024, 2048,
                        (long)by * 128, (long)bx * 128, (long)bz * 1024 * 2048,
                        nullptr, wvb, 1.0f, false, nullptr, nullptr, smem);
    }
}

// G3: P_unnorm[b] = exp(Q[b] @ K[b]^T / 32) -> bf16, rowsum accumulated.  256 blocks (1/CU)
__global__ __launch_bounds__(512, 2)
void gemm8_qkt(const u16* __restrict__ QK, u16* __restrict__ Pbuf,
               float* __restrict__ rsum)
{
    u32 id = blockIdx.x;
    id = (id & 7u) * 32u + (id >> 3);          // XCD-contiguous remap (256 % 8 == 0)
    u32 bz = id >> 6, q = id & 63u, bx = q & 7u, by = q >> 3;
    __shared__ alignas(16) u16 smem[65536];
    const u16* base = QK + (long)bz * 2048 * 2048;
    gemm8_core<true, true>(base, base + 1024, Pbuf, 1024, 2048, 2048, 2048,
                           (long)by * 256, (long)bx * 256, (long)bz * 2048 * 2048,
                           nullptr, nullptr, 0.03125f, false,
                           rsum + (long)bz * 2048, smem);
}

// G5: out[b] = (P[b] @ VT[b]^T) / rowsum on the 8-phase 256x128 core.
// Grid 256 = 4 bz x 8 by (M=2048/256) x 8 bx (N=1024/128), 1 block/CU, zero tail.
__global__ __launch_bounds__(512, 2)
void gemm8_pv(const u16* __restrict__ Pbuf, const u16* __restrict__ VT,
              float* __restrict__ out, const float* __restrict__ rsum)
{
    u32 id = blockIdx.x;
    id = (id & 7u) * 32u + (id >> 3);          // XCD-contiguous remap (256 % 8 == 0)
    u32 bz = id >> 6, q = id & 63u, by = q >> 3, bx = q & 7u;
    __shared__ alignas(16) u16 smem[49152];    // 96 KiB ring
    gemm8n128_core(Pbuf + (long)bz * 2048 * 2048,
                   VT   + (long)bz * 1024 * 2048,
                   out, 2048, 2048, 2048, 1024,
                   (long)by * 256, (long)bx * 128, (long)bz * 2048 * 1024,
                   rsum + (long)bz * 2048, smem);
}

// ---------------------------------------------------------------- launch
extern "C" void kernel_launch(void* const* d_in, const int* in_sizes, int n_in,
                              void* d_out, int out_size, void* d_ws, size_t ws_size,
                              hipStream_t stream)
{
    const float* x   = (const float*)d_in[0];
    const float* wqw = (const float*)d_in[1];
    const float* wqb = (const float*)d_in[2];
    const float* wkw = (const float*)d_in[3];
    const float* wkb = (const float*)d_in[4];
    const float* wvw = (const float*)d_in[5];
    const float* wvb = (const float*)d_in[6];
    float* out = (float*)d_out;

    char* ws = (char*)d_ws;
    const size_t MB = 1ull << 20;
    u16*   Pbuf = (u16*)(ws + 64 * MB);      // 32MB [4][2048][2048] bf16 P_unnorm = exp(S)
    u16*   QK   = (u16*)(ws + 96 * MB);      // 32MB [8192][2048] bf16 (Q | K), RoPE applied
    u16*   VT   = (u16*)(ws + 128 * MB);     // 16MB [4][1024][2048] bf16 (V transposed)
    float* rsum = (float*)(ws + 144 * MB);   // 32KB [8192] f32 softmax row sums
    u16*   xb    = (u16*)(ws + 0);           // 16MB [8192][1024]
    u16*   wqk   = (u16*)(ws + 16 * MB);     //  4MB [2048][1024]
    u16*   wvbuf = (u16*)(ws + 20 * MB);     //  2MB [1024][1024]
    float* bqk   = (float*)(ws + 22 * MB);   //  8KB [2048]

    // 1. all dtype conversions + bias concat + rowsum zeroing
    cvt_all<<<dim3(11280), 256, 0, stream>>>(x, xb, wqw, wkw, wvw,
                                             wqk, wqk + 1024 * 1024, wvbuf,
                                             wqb, wkb, bqk, rsum);

    // 2. fused G1 + G2 (2-phase 128^2 core, 4 blocks/CU)
    gemm_fused12<<<dim3(1536), 256, 0, stream>>>(xb, wqk, wvbuf, QK, VT, bqk, wvb);

    // 3. G3 on the 8-phase 256^2 core (256 blocks, zero tail)
    gemm8_qkt<<<dim3(256), 512, 0, stream>>>(QK, Pbuf, rsum);

    // 4. G5 on the 8-phase 256x128 core (256 blocks, zero tail)
    gemm8_pv<<<dim3(256), 512, 0, stream>>>(Pbuf, VT, out, rsum);

    (void)in_sizes; (void)n_in; (void)out_size; (void)ws_size;
}